// Round 1
// baseline (541.176 us; speedup 1.0000x reference)
//
#include <hip/hip_runtime.h>
#include <math.h>

#define BS   32
#define NV   6
#define MF   12
#define MT   16
#define NF   1992
#define NR   11
#define HID  128
#define RED  256
#define OUTD 90
#define GAMMA 0.1f

// workspace layout (float offsets)
#define WS_HG    0                      // 32*256
#define WS_HP    (WS_HG + BS*RED)       // 32*256
#define WS_ATTN  (WS_HP + BS*RED)       // 2304
#define WS_FSUM  (WS_ATTN + BS*NV*MF)   // 2304
#define WS_REMB  (WS_FSUM + BS*NV*MF)   // 1992*256
#define WS_REDGE (WS_REMB + NF*RED)     // 11*256

// ---------------- kernel A: reduced_emb / reduced_edge ----------------
__global__ void k_reduce_emb(const float* __restrict__ emb, const float* __restrict__ W_edge,
                             const float* __restrict__ W_v, const float* __restrict__ W_r,
                             const float* __restrict__ b_v, const float* __restrict__ b_r,
                             float* __restrict__ remb, float* __restrict__ redge) {
    __shared__ float row[HID];
    int blk = blockIdx.x;
    int tid = threadIdx.x;              // 256 = one r each
    const float *src, *W, *bias;
    float* dst;
    if (blk < NF) { src = emb + (size_t)blk * HID;        W = W_v; bias = b_v; dst = remb  + (size_t)blk * RED; }
    else          { src = W_edge + (size_t)(blk-NF) * HID; W = W_r; bias = b_r; dst = redge + (size_t)(blk-NF) * RED; }
    if (tid < HID) row[tid] = src[tid];
    __syncthreads();
    const float* wrow = W + (size_t)tid * HID;
    float acc = bias[tid];
    #pragma unroll 4
    for (int k = 0; k < HID; ++k) acc += row[k] * wrow[k];
    dst[tid] = acc;
}

// ---------------- kernel B: alpha/beta -> attn, fsum ----------------
__global__ void k_attn(const float* __restrict__ feat, const float* __restrict__ W_alpha,
                       const float* __restrict__ b_alpha, const float* __restrict__ W_beta,
                       const float* __restrict__ b_beta,
                       float* __restrict__ attn_ws, float* __restrict__ fsum_ws) {
    int bv  = blockIdx.x;               // 0..191 (b*6+v)
    int v   = bv % NV;
    int tid = threadIdx.x;              // 256
    __shared__ float red_a[256], red_b[256];
    __shared__ float dot12[MF], fs12[MF];
    const float* base = feat + (size_t)bv * MF * NF;
    for (int m = 0; m < MF; ++m) {
        const float* rw = base + (size_t)m * NF;
        float da = 0.f, fs = 0.f;
        for (int n = tid; n < NF; n += 256) {
            float x = rw[n];
            da += W_alpha[n] * x;
            fs += x;
        }
        red_a[tid] = da; red_b[tid] = fs;
        __syncthreads();
        for (int s = 128; s > 0; s >>= 1) {
            if (tid < s) { red_a[tid] += red_a[tid+s]; red_b[tid] += red_b[tid+s]; }
            __syncthreads();
        }
        if (tid == 0) { dot12[m] = red_a[0]; fs12[m] = red_b[0]; }
        __syncthreads();
    }
    if (tid == 0) {
        float logits[MF];
        float mx = -1e30f;
        for (int m = 0; m < MF; ++m) { logits[m] = dot12[m] + b_alpha[m]; mx = fmaxf(mx, logits[m]); }
        float s = 0.f;
        for (int m = 0; m < MF; ++m) { logits[m] = expf(logits[m] - mx); s += logits[m]; }
        float inv = 1.f / s;
        float bdot = 0.f;
        for (int m = 0; m < MF; ++m) { logits[m] *= inv; bdot += W_beta[m] * logits[m]; }
        float lamb = expf(-GAMMA * (float)(NV - v));
        float beta = tanhf(bdot + b_beta[v]) * lamb;
        for (int m = 0; m < MF; ++m) {
            attn_ws[bv*MF + m] = logits[m] * beta;
            fsum_ws[bv*MF + m] = fs12[m];
        }
    }
}

// ---------------- kernel C: the big aggregation ----------------
#define NZCAP 1024
__global__ __launch_bounds__(256) void k_agg(
        const float* __restrict__ nbr, const float* __restrict__ rel,
        const float* __restrict__ remb, const float* __restrict__ redge,
        const float* __restrict__ attn_ws, const float* __restrict__ fsum_ws,
        const float* __restrict__ W_l, const float* __restrict__ b_l,
        float* __restrict__ h_g, float* __restrict__ h_p) {
    int bvm = blockIdx.x;               // 0..2303
    int b   = bvm / (NV * MF);
    int tid = threadIdx.x;              // 256
    __shared__ __align__(16) float nsum[NF];   // 1992 floats = 498 float4
    __shared__ int   nz_n[NZCAP];
    __shared__ float nz_v[NZCAP];
    __shared__ float rsum[NR];
    __shared__ int   cnt;
    if (tid == 0) cnt = 0;

    // --- stream 16 x 1992 neighbor rows, sum over t (float4 coalesced) ---
    const float4* base = (const float4*)(nbr + (size_t)bvm * MT * NF); // row = 498 float4
    float4 a0 = make_float4(0.f, 0.f, 0.f, 0.f);
    float4 a1 = make_float4(0.f, 0.f, 0.f, 0.f);
    const bool has1 = (tid + 256) < 498;
    #pragma unroll 4
    for (int t = 0; t < MT; ++t) {
        const float4* r4 = base + t * 498;
        float4 x = r4[tid];
        a0.x += x.x; a0.y += x.y; a0.z += x.z; a0.w += x.w;
        if (has1) {
            float4 y = r4[tid + 256];
            a1.x += y.x; a1.y += y.y; a1.z += y.z; a1.w += y.w;
        }
    }
    ((float4*)nsum)[tid] = a0;
    if (has1) ((float4*)nsum)[tid + 256] = a1;

    // --- relation sums over t (11 rels) ---
    if (tid < NR) {
        const float* rb = rel + (size_t)bvm * MT * NR;
        float s = 0.f;
        #pragma unroll
        for (int t = 0; t < MT; ++t) s += rb[t*NR + tid];
        rsum[tid] = s;
    }
    __syncthreads();

    // --- compact nonzeros of nsum (density ~0.001 => ~32 entries) ---
    {
        float vals0[4] = {a0.x, a0.y, a0.z, a0.w};
        int nb = tid * 4;
        #pragma unroll
        for (int c = 0; c < 4; ++c) {
            if (vals0[c] != 0.f) {
                int p = atomicAdd(&cnt, 1);
                if (p < NZCAP) { nz_n[p] = nb + c; nz_v[p] = vals0[c]; }
            }
        }
        if (has1) {
            float vals1[4] = {a1.x, a1.y, a1.z, a1.w};
            nb = (tid + 256) * 4;
            #pragma unroll
            for (int c = 0; c < 4; ++c) {
                if (vals1[c] != 0.f) {
                    int p = atomicAdd(&cnt, 1);
                    if (p < NZCAP) { nz_n[p] = nb + c; nz_v[p] = vals1[c]; }
                }
            }
        }
    }
    __syncthreads();

    // --- each thread owns one r; sparse gather matvec + edge term ---
    int r = tid;
    int c = min(cnt, NZCAP);
    float node = 0.f;
    for (int i = 0; i < c; ++i)
        node += nz_v[i] * remb[(size_t)nz_n[i] * RED + r];   // coalesced over r
    float edge = 0.f;
    #pragma unroll
    for (int j = 0; j < NR; ++j)
        edge += rsum[j] * redge[j*RED + r];
    float a  = attn_ws[bvm];
    float fs = fsum_ws[bvm];
    float agg = a * node + edge;
    float h = fmaxf(0.f, W_l[(size_t)r * RED + r] * agg + b_l[r]);
    atomicAdd(&h_g[b*RED + r], h);
    atomicAdd(&h_p[b*RED + r], fs * h);
}

// ---------------- kernel D: final FC + sigmoid ----------------
__global__ void k_out(const float* __restrict__ h_g, const float* __restrict__ h_p,
                      const float* __restrict__ fc_W, const float* __restrict__ fc_b,
                      float* __restrict__ out) {
    int b   = blockIdx.x;
    int tid = threadIdx.x;              // 128
    __shared__ float z[2*RED];
    for (int j = tid; j < RED; j += 128) {
        z[j]       = h_g[b*RED + j];
        z[RED + j] = h_p[b*RED + j];
    }
    __syncthreads();
    if (tid < OUTD) {
        const float* w = fc_W + (size_t)tid * (2*RED);
        float acc = fc_b[tid];
        for (int j = 0; j < 2*RED; ++j) acc += z[j] * w[j];
        out[b*OUTD + tid] = 1.f / (1.f + expf(-acc));
    }
}

extern "C" void kernel_launch(void* const* d_in, const int* in_sizes, int n_in,
                              void* d_out, int out_size, void* d_ws, size_t ws_size,
                              hipStream_t stream) {
    const float* feat    = (const float*)d_in[0];
    const float* nbr     = (const float*)d_in[1];
    const float* rel     = (const float*)d_in[2];
    const float* emb     = (const float*)d_in[3];
    const float* W_edge  = (const float*)d_in[4];
    const float* W_v     = (const float*)d_in[5];
    const float* W_r     = (const float*)d_in[6];
    const float* b_v     = (const float*)d_in[7];
    const float* b_r     = (const float*)d_in[8];
    const float* W_alpha = (const float*)d_in[9];
    const float* b_alpha = (const float*)d_in[10];
    const float* W_beta  = (const float*)d_in[11];
    const float* b_beta  = (const float*)d_in[12];
    const float* W_l     = (const float*)d_in[13];
    const float* b_l     = (const float*)d_in[14];
    const float* fc_W    = (const float*)d_in[15];
    const float* fc_b    = (const float*)d_in[16];

    float* ws    = (float*)d_ws;
    float* hg    = ws + WS_HG;
    float* hp    = ws + WS_HP;
    float* attn  = ws + WS_ATTN;
    float* fsum  = ws + WS_FSUM;
    float* remb  = ws + WS_REMB;
    float* redge = ws + WS_REDGE;

    // zero the accumulators (hg+hp are contiguous)
    hipMemsetAsync(hg, 0, (size_t)2 * BS * RED * sizeof(float), stream);

    k_reduce_emb<<<NF + NR, 256, 0, stream>>>(emb, W_edge, W_v, W_r, b_v, b_r, remb, redge);
    k_attn<<<BS * NV, 256, 0, stream>>>(feat, W_alpha, b_alpha, W_beta, b_beta, attn, fsum);
    k_agg<<<BS * NV * MF, 256, 0, stream>>>(nbr, rel, remb, redge, attn, fsum, W_l, b_l, hg, hp);
    k_out<<<BS, 128, 0, stream>>>(hg, hp, fc_W, fc_b, (float*)d_out);
}

// Round 2
// 516.903 us; speedup vs baseline: 1.0470x; 1.0470x over previous
//
#include <hip/hip_runtime.h>
#include <math.h>

#define BS   32
#define NV   6
#define MF   12
#define MT   16
#define NF   1992
#define NR   11
#define HID  128
#define RED  256
#define OUTD 90
#define GAMMA 0.1f

// workspace layout (float offsets)
#define WS_HG    0                        // 32*256
#define WS_HP    (WS_HG + BS*RED)         // 32*256
#define WS_ATTN  (WS_HP + BS*RED)         // 2304
#define WS_FSUM  (WS_ATTN + BS*NV*MF)     // 2304
#define WS_REMB  (WS_FSUM + BS*NV*MF)     // 1992*256
#define WS_REDGE (WS_REMB + NF*RED)       // 11*256
#define WS_WTV   (WS_REDGE + NR*RED)      // 128*256  (W_v^T, k-major)
#define WS_WTR   (WS_WTV + HID*RED)       // 128*256  (W_r^T, k-major)
#define WS_FCWT  (WS_WTR + HID*RED)       // 512*90   (fc_W^T, j-major)

#define N_WTV  (HID*RED)                  // 32768
#define N_WTR  (HID*RED)                  // 32768
#define N_FCWT (2*RED*OUTD)               // 46080
#define PREP_ELEMS (N_WTV + N_WTR + N_FCWT)          // 111616
#define PREP_BLOCKS ((PREP_ELEMS + 255) / 256)       // 436

// ---------- kernel 1: transposes (coalesced-write) + attention ----------
__global__ __launch_bounds__(256) void k_prep_attn(
        const float* __restrict__ W_v, const float* __restrict__ W_r,
        const float* __restrict__ fc_W,
        const float* __restrict__ feat, const float* __restrict__ W_alpha,
        const float* __restrict__ b_alpha, const float* __restrict__ W_beta,
        const float* __restrict__ b_beta,
        float* __restrict__ WT_v, float* __restrict__ WT_r, float* __restrict__ fcWT,
        float* __restrict__ attn_ws, float* __restrict__ fsum_ws) {
    int blk = blockIdx.x;
    int tid = threadIdx.x;
    if (blk < PREP_BLOCKS) {
        int i = blk * 256 + tid;
        if (i < N_WTV) {                      // WT_v[k*256+r] = W_v[r*128+k]
            int k = i >> 8, r = i & 255;
            WT_v[i] = W_v[r * HID + k];
        } else if (i < N_WTV + N_WTR) {
            int j = i - N_WTV;
            int k = j >> 8, r = j & 255;
            WT_r[j] = W_r[r * HID + k];
        } else if (i < PREP_ELEMS) {
            int j = i - (N_WTV + N_WTR);      // j = jj*90 + o
            int jj = j / OUTD, o = j - jj * OUTD;
            fcWT[j] = fc_W[o * (2 * RED) + jj];
        }
        return;
    }
    // ---- attention part: one block per (b,v), one wave per m ----
    int bv   = blk - PREP_BLOCKS;             // 0..191
    int v    = bv % NV;
    int wave = tid >> 6;
    int lane = tid & 63;
    __shared__ float dot12[MF], fs12[MF];
    const float* base = feat + (size_t)bv * MF * NF;
    for (int m = wave; m < MF; m += 4) {
        const float4* rw = (const float4*)(base + (size_t)m * NF);   // 498 float4
        const float4* wa = (const float4*)W_alpha;
        float da = 0.f, fs = 0.f;
        for (int i = lane; i < NF / 4; i += 64) {
            float4 x = rw[i];
            float4 w = wa[i];
            da += w.x * x.x + w.y * x.y + w.z * x.z + w.w * x.w;
            fs += x.x + x.y + x.z + x.w;
        }
        #pragma unroll
        for (int off = 32; off > 0; off >>= 1) {
            da += __shfl_xor(da, off);
            fs += __shfl_xor(fs, off);
        }
        if (lane == 0) { dot12[m] = da; fs12[m] = fs; }
    }
    __syncthreads();
    if (tid == 0) {
        float logits[MF];
        float mx = -1e30f;
        for (int m = 0; m < MF; ++m) { logits[m] = dot12[m] + b_alpha[m]; mx = fmaxf(mx, logits[m]); }
        float s = 0.f;
        for (int m = 0; m < MF; ++m) { logits[m] = expf(logits[m] - mx); s += logits[m]; }
        float inv = 1.f / s;
        float bdot = 0.f;
        for (int m = 0; m < MF; ++m) { logits[m] *= inv; bdot += W_beta[m] * logits[m]; }
        float lamb = expf(-GAMMA * (float)(NV - v));
        float beta = tanhf(bdot + b_beta[v]) * lamb;
        for (int m = 0; m < MF; ++m) {
            attn_ws[bv * MF + m] = logits[m] * beta;
            fsum_ws[bv * MF + m] = fs12[m];
        }
    }
}

// ---------- kernel 2: reduced_emb (4 rows/block) + reduced_edge ----------
#define NPB 4
#define NODE_BLOCKS (NF / NPB)   // 498
__global__ __launch_bounds__(256) void k_reduce(
        const float* __restrict__ emb, const float* __restrict__ W_edge,
        const float* __restrict__ WT_v, const float* __restrict__ WT_r,
        const float* __restrict__ b_v, const float* __restrict__ b_r,
        float* __restrict__ remb, float* __restrict__ redge) {
    int blk = blockIdx.x;
    int tid = threadIdx.x;                    // r = tid
    if (blk < NODE_BLOCKS) {
        __shared__ float rows[NPB][HID];
        int n0 = blk * NPB;
        for (int i = tid; i < NPB * HID; i += 256)
            rows[i >> 7][i & 127] = emb[(size_t)n0 * HID + i];
        __syncthreads();
        float bv0 = b_v[tid];
        float a0 = bv0, a1 = bv0, a2 = bv0, a3 = bv0;
        #pragma unroll 4
        for (int k = 0; k < HID; ++k) {
            float w = WT_v[k * RED + tid];    // coalesced, L2-resident
            a0 += rows[0][k] * w;
            a1 += rows[1][k] * w;
            a2 += rows[2][k] * w;
            a3 += rows[3][k] * w;
        }
        remb[(size_t)(n0 + 0) * RED + tid] = a0;
        remb[(size_t)(n0 + 1) * RED + tid] = a1;
        remb[(size_t)(n0 + 2) * RED + tid] = a2;
        remb[(size_t)(n0 + 3) * RED + tid] = a3;
    } else {
        int e = blk - NODE_BLOCKS;            // 0..10
        __shared__ float row[HID];
        if (tid < HID) row[tid] = W_edge[e * HID + tid];
        __syncthreads();
        float acc = b_r[tid];
        #pragma unroll 4
        for (int k = 0; k < HID; ++k)
            acc += row[k] * WT_r[k * RED + tid];
        redge[e * RED + tid] = acc;
    }
}

// ---------- kernel 3: big aggregation ----------
#define NZCAP 1024
__global__ __launch_bounds__(256) void k_agg(
        const float* __restrict__ nbr, const float* __restrict__ rel,
        const float* __restrict__ remb, const float* __restrict__ redge,
        const float* __restrict__ attn_ws, const float* __restrict__ fsum_ws,
        const float* __restrict__ W_l, const float* __restrict__ b_l,
        float* __restrict__ h_g, float* __restrict__ h_p) {
    int bvm = blockIdx.x;                     // 0..2303
    int b   = bvm / (NV * MF);
    int tid = threadIdx.x;                    // 256
    __shared__ int   nz_n[NZCAP];
    __shared__ float nz_v[NZCAP];
    __shared__ float rsum[NR];
    __shared__ int   cnt;
    if (tid == 0) cnt = 0;

    // stream 16 x 1992 neighbor rows, sum over t (float4 coalesced)
    const float4* base = (const float4*)(nbr + (size_t)bvm * MT * NF);  // row = 498 float4
    float4 a0 = make_float4(0.f, 0.f, 0.f, 0.f);
    float4 a1 = make_float4(0.f, 0.f, 0.f, 0.f);
    const bool has1 = (tid + 256) < (NF / 4);
    #pragma unroll 4
    for (int t = 0; t < MT; ++t) {
        const float4* r4 = base + t * (NF / 4);
        float4 x = r4[tid];
        a0.x += x.x; a0.y += x.y; a0.z += x.z; a0.w += x.w;
        if (has1) {
            float4 y = r4[tid + 256];
            a1.x += y.x; a1.y += y.y; a1.z += y.z; a1.w += y.w;
        }
    }

    // relation sums over t
    if (tid < NR) {
        const float* rb = rel + (size_t)bvm * MT * NR;
        float s = 0.f;
        #pragma unroll
        for (int t = 0; t < MT; ++t) s += rb[t * NR + tid];
        rsum[tid] = s;
    }
    __syncthreads();   // also covers cnt=0 init

    // compact nonzeros (~32 of 1992)
    {
        float vals0[4] = {a0.x, a0.y, a0.z, a0.w};
        int nb = tid * 4;
        #pragma unroll
        for (int c = 0; c < 4; ++c)
            if (vals0[c] != 0.f) {
                int p = atomicAdd(&cnt, 1);
                if (p < NZCAP) { nz_n[p] = nb + c; nz_v[p] = vals0[c]; }
            }
        if (has1) {
            float vals1[4] = {a1.x, a1.y, a1.z, a1.w};
            nb = (tid + 256) * 4;
            #pragma unroll
            for (int c = 0; c < 4; ++c)
                if (vals1[c] != 0.f) {
                    int p = atomicAdd(&cnt, 1);
                    if (p < NZCAP) { nz_n[p] = nb + c; nz_v[p] = vals1[c]; }
                }
        }
    }
    __syncthreads();

    // each thread owns one r: sparse gather matvec + edge term
    int r = tid;
    int c = min(cnt, NZCAP);
    float node = 0.f;
    for (int i = 0; i < c; ++i)
        node += nz_v[i] * remb[(size_t)nz_n[i] * RED + r];   // coalesced over r
    float edge = 0.f;
    #pragma unroll
    for (int j = 0; j < NR; ++j)
        edge += rsum[j] * redge[j * RED + r];
    float a  = attn_ws[bvm];
    float fs = fsum_ws[bvm];
    float agg = a * node + edge;
    float h = fmaxf(0.f, W_l[(size_t)r * RED + r] * agg + b_l[r]);
    atomicAdd(&h_g[b * RED + r], h);
    atomicAdd(&h_p[b * RED + r], fs * h);
}

// ---------- kernel 4: final FC + sigmoid (transposed weights) ----------
__global__ void k_out(const float* __restrict__ h_g, const float* __restrict__ h_p,
                      const float* __restrict__ fcWT, const float* __restrict__ fc_b,
                      float* __restrict__ out) {
    int b   = blockIdx.x;
    int tid = threadIdx.x;                    // 128
    __shared__ float z[2 * RED];
    for (int j = tid; j < RED; j += 128) {
        z[j]       = h_g[b * RED + j];
        z[RED + j] = h_p[b * RED + j];
    }
    __syncthreads();
    if (tid < OUTD) {
        float acc = fc_b[tid];
        #pragma unroll 4
        for (int j = 0; j < 2 * RED; ++j)
            acc += z[j] * fcWT[j * OUTD + tid];   // coalesced over tid
        out[b * OUTD + tid] = 1.f / (1.f + expf(-acc));
    }
}

extern "C" void kernel_launch(void* const* d_in, const int* in_sizes, int n_in,
                              void* d_out, int out_size, void* d_ws, size_t ws_size,
                              hipStream_t stream) {
    const float* feat    = (const float*)d_in[0];
    const float* nbr     = (const float*)d_in[1];
    const float* rel     = (const float*)d_in[2];
    const float* emb     = (const float*)d_in[3];
    const float* W_edge  = (const float*)d_in[4];
    const float* W_v     = (const float*)d_in[5];
    const float* W_r     = (const float*)d_in[6];
    const float* b_v     = (const float*)d_in[7];
    const float* b_r     = (const float*)d_in[8];
    const float* W_alpha = (const float*)d_in[9];
    const float* b_alpha = (const float*)d_in[10];
    const float* W_beta  = (const float*)d_in[11];
    const float* b_beta  = (const float*)d_in[12];
    const float* W_l     = (const float*)d_in[13];
    const float* b_l     = (const float*)d_in[14];
    const float* fc_b    = (const float*)d_in[16];
    const float* fc_W    = (const float*)d_in[15];

    float* ws    = (float*)d_ws;
    float* hg    = ws + WS_HG;
    float* hp    = ws + WS_HP;
    float* attn  = ws + WS_ATTN;
    float* fsum  = ws + WS_FSUM;
    float* remb  = ws + WS_REMB;
    float* redge = ws + WS_REDGE;
    float* WT_v  = ws + WS_WTV;
    float* WT_r  = ws + WS_WTR;
    float* fcWT  = ws + WS_FCWT;

    hipMemsetAsync(hg, 0, (size_t)2 * BS * RED * sizeof(float), stream);

    k_prep_attn<<<PREP_BLOCKS + BS * NV, 256, 0, stream>>>(
        W_v, W_r, fc_W, feat, W_alpha, b_alpha, W_beta, b_beta,
        WT_v, WT_r, fcWT, attn, fsum);
    k_reduce<<<NODE_BLOCKS + NR, 256, 0, stream>>>(
        emb, W_edge, WT_v, WT_r, b_v, b_r, remb, redge);
    k_agg<<<BS * NV * MF, 256, 0, stream>>>(
        nbr, rel, remb, redge, attn, fsum, W_l, b_l, hg, hp);
    k_out<<<BS, 128, 0, stream>>>(hg, hp, fcWT, fc_b, (float*)d_out);
}

// Round 3
// 454.514 us; speedup vs baseline: 1.1907x; 1.1373x over previous
//
#include <hip/hip_runtime.h>
#include <math.h>

#define BS   32
#define NV   6
#define MF   12
#define MT   16
#define NF   1992
#define NR   11
#define HID  128
#define RED  256
#define OUTD 90
#define GAMMA 0.1f

typedef float f4_t __attribute__((ext_vector_type(4)));

// workspace layout (float offsets)
#define WS_HG    0                        // 32*256
#define WS_HP    (WS_HG + BS*RED)         // 32*256
#define WS_ATTN  (WS_HP + BS*RED)         // 2304
#define WS_FSUM  (WS_ATTN + BS*NV*MF)     // 2304
#define WS_REMB  (WS_FSUM + BS*NV*MF)     // 1992*256
#define WS_REDGE (WS_REMB + NF*RED)       // 11*256
#define WS_WTV   (WS_REDGE + NR*RED)      // 128*256  (W_v^T, k-major)
#define WS_WTR   (WS_WTV + HID*RED)       // 128*256  (W_r^T, k-major)
#define WS_FCWT  (WS_WTR + HID*RED)       // 512*90   (fc_W^T, j-major)

#define N_ZERO (2*BS*RED)                 // 16384 (hg+hp contiguous)
#define N_WTV  (HID*RED)                  // 32768
#define N_WTR  (HID*RED)                  // 32768
#define N_FCWT (2*RED*OUTD)               // 46080
#define PREP_ELEMS (N_ZERO + N_WTV + N_WTR + N_FCWT)   // 128000
#define PREP_BLOCKS (PREP_ELEMS / 256)                 // 500

// ---------- kernel 1: zero accumulators + transposes + attention ----------
__global__ __launch_bounds__(256) void k_prep_attn(
        const float* __restrict__ W_v, const float* __restrict__ W_r,
        const float* __restrict__ fc_W,
        const float* __restrict__ feat, const float* __restrict__ W_alpha,
        const float* __restrict__ b_alpha, const float* __restrict__ W_beta,
        const float* __restrict__ b_beta,
        float* __restrict__ ws_base,
        float* __restrict__ WT_v, float* __restrict__ WT_r, float* __restrict__ fcWT,
        float* __restrict__ attn_ws, float* __restrict__ fsum_ws) {
    int blk = blockIdx.x;
    int tid = threadIdx.x;
    if (blk < PREP_BLOCKS) {
        int i = blk * 256 + tid;
        if (i < N_ZERO) {                          // zero hg+hp
            ws_base[i] = 0.f;
        } else if (i < N_ZERO + N_WTV) {           // WT_v[k*256+r] = W_v[r*128+k]
            int j = i - N_ZERO;
            int k = j >> 8, r = j & 255;
            WT_v[j] = W_v[r * HID + k];
        } else if (i < N_ZERO + N_WTV + N_WTR) {
            int j = i - (N_ZERO + N_WTV);
            int k = j >> 8, r = j & 255;
            WT_r[j] = W_r[r * HID + k];
        } else {
            int j = i - (N_ZERO + N_WTV + N_WTR);  // j = jj*90 + o
            int jj = j / OUTD, o = j - jj * OUTD;
            fcWT[j] = fc_W[o * (2 * RED) + jj];
        }
        return;
    }
    // ---- attention part: one block per (b,v), one wave per m ----
    int bv   = blk - PREP_BLOCKS;                  // 0..191
    int v    = bv % NV;
    int wave = tid >> 6;
    int lane = tid & 63;
    __shared__ float dot12[MF], fs12[MF];
    const float* base = feat + (size_t)bv * MF * NF;
    for (int m = wave; m < MF; m += 4) {
        const float4* rw = (const float4*)(base + (size_t)m * NF);   // 498 float4
        const float4* wa = (const float4*)W_alpha;
        float da = 0.f, fs = 0.f;
        for (int i = lane; i < NF / 4; i += 64) {
            float4 x = rw[i];
            float4 w = wa[i];
            da += w.x * x.x + w.y * x.y + w.z * x.z + w.w * x.w;
            fs += x.x + x.y + x.z + x.w;
        }
        #pragma unroll
        for (int off = 32; off > 0; off >>= 1) {
            da += __shfl_xor(da, off);
            fs += __shfl_xor(fs, off);
        }
        if (lane == 0) { dot12[m] = da; fs12[m] = fs; }
    }
    __syncthreads();
    if (tid == 0) {
        float logits[MF];
        float mx = -1e30f;
        for (int m = 0; m < MF; ++m) { logits[m] = dot12[m] + b_alpha[m]; mx = fmaxf(mx, logits[m]); }
        float s = 0.f;
        for (int m = 0; m < MF; ++m) { logits[m] = expf(logits[m] - mx); s += logits[m]; }
        float inv = 1.f / s;
        float bdot = 0.f;
        for (int m = 0; m < MF; ++m) { logits[m] *= inv; bdot += W_beta[m] * logits[m]; }
        float lamb = expf(-GAMMA * (float)(NV - v));
        float beta = tanhf(bdot + b_beta[v]) * lamb;
        for (int m = 0; m < MF; ++m) {
            attn_ws[bv * MF + m] = logits[m] * beta;
            fsum_ws[bv * MF + m] = fs12[m];
        }
    }
}

// ---------- kernel 2: reduced_emb (8 rows/block) + reduced_edge ----------
#define NPB 8
#define NODE_BLOCKS (NF / NPB)   // 249
__global__ __launch_bounds__(256) void k_reduce(
        const float* __restrict__ emb, const float* __restrict__ W_edge,
        const float* __restrict__ WT_v, const float* __restrict__ WT_r,
        const float* __restrict__ b_v, const float* __restrict__ b_r,
        float* __restrict__ remb, float* __restrict__ redge) {
    int blk = blockIdx.x;
    int tid = threadIdx.x;                    // r = tid
    if (blk < NODE_BLOCKS) {
        __shared__ float rows[NPB][HID];
        int n0 = blk * NPB;
        for (int i = tid; i < NPB * HID; i += 256)
            rows[i >> 7][i & 127] = emb[(size_t)n0 * HID + i];
        __syncthreads();
        float bv0 = b_v[tid];
        float a0 = bv0, a1 = bv0, a2 = bv0, a3 = bv0;
        float a4 = bv0, a5 = bv0, a6 = bv0, a7 = bv0;
        #pragma unroll 4
        for (int k = 0; k < HID; ++k) {
            float w = WT_v[k * RED + tid];    // coalesced, L2-resident
            a0 += rows[0][k] * w;
            a1 += rows[1][k] * w;
            a2 += rows[2][k] * w;
            a3 += rows[3][k] * w;
            a4 += rows[4][k] * w;
            a5 += rows[5][k] * w;
            a6 += rows[6][k] * w;
            a7 += rows[7][k] * w;
        }
        float* dst = remb + (size_t)n0 * RED + tid;
        dst[0*RED] = a0; dst[1*RED] = a1; dst[2*RED] = a2; dst[3*RED] = a3;
        dst[4*RED] = a4; dst[5*RED] = a5; dst[6*RED] = a6; dst[7*RED] = a7;
    } else {
        int e = blk - NODE_BLOCKS;            // 0..10
        __shared__ float row[HID];
        if (tid < HID) row[tid] = W_edge[e * HID + tid];
        __syncthreads();
        float acc = b_r[tid];
        #pragma unroll 4
        for (int k = 0; k < HID; ++k)
            acc += row[k] * WT_r[k * RED + tid];
        redge[e * RED + tid] = acc;
    }
}

// ---------- kernel 3: big aggregation ----------
#define NZCAP 1024
__global__ __launch_bounds__(256) void k_agg(
        const float* __restrict__ nbr, const float* __restrict__ rel,
        const float* __restrict__ remb, const float* __restrict__ redge,
        const float* __restrict__ attn_ws, const float* __restrict__ fsum_ws,
        const float* __restrict__ W_l, const float* __restrict__ b_l,
        float* __restrict__ h_g, float* __restrict__ h_p) {
    int bvm = blockIdx.x;                     // 0..2303
    int b   = bvm / (NV * MF);
    int tid = threadIdx.x;                    // 256
    __shared__ int   nz_n[NZCAP];
    __shared__ float nz_v[NZCAP];
    __shared__ float rsum[NR];
    __shared__ int   cnt;
    if (tid == 0) cnt = 0;

    // stream 16 x 1992 neighbor rows, sum over t (nontemporal float4)
    const f4_t* base = (const f4_t*)(nbr + (size_t)bvm * MT * NF);  // row = 498 f4
    f4_t a0 = (f4_t)(0.f);
    f4_t a1 = (f4_t)(0.f);
    const bool has1 = (tid + 256) < (NF / 4);
    #pragma unroll 4
    for (int t = 0; t < MT; ++t) {
        const f4_t* r4 = base + t * (NF / 4);
        f4_t x = __builtin_nontemporal_load(r4 + tid);
        a0 += x;
        if (has1) {
            f4_t y = __builtin_nontemporal_load(r4 + tid + 256);
            a1 += y;
        }
    }

    // relation sums over t
    if (tid < NR) {
        const float* rb = rel + (size_t)bvm * MT * NR;
        float s = 0.f;
        #pragma unroll
        for (int t = 0; t < MT; ++t) s += rb[t * NR + tid];
        rsum[tid] = s;
    }
    __syncthreads();   // also covers cnt=0 init

    // compact nonzeros (~32 of 1992)
    {
        int nb = tid * 4;
        #pragma unroll
        for (int c = 0; c < 4; ++c)
            if (a0[c] != 0.f) {
                int p = atomicAdd(&cnt, 1);
                if (p < NZCAP) { nz_n[p] = nb + c; nz_v[p] = a0[c]; }
            }
        if (has1) {
            nb = (tid + 256) * 4;
            #pragma unroll
            for (int c = 0; c < 4; ++c)
                if (a1[c] != 0.f) {
                    int p = atomicAdd(&cnt, 1);
                    if (p < NZCAP) { nz_n[p] = nb + c; nz_v[p] = a1[c]; }
                }
        }
    }
    __syncthreads();

    // each thread owns one r: sparse gather matvec + edge term
    int r = tid;
    int c = min(cnt, NZCAP);
    float node = 0.f;
    for (int i = 0; i < c; ++i)
        node += nz_v[i] * remb[(size_t)nz_n[i] * RED + r];   // coalesced over r
    float edge = 0.f;
    #pragma unroll
    for (int j = 0; j < NR; ++j)
        edge += rsum[j] * redge[j * RED + r];
    float a  = attn_ws[bvm];
    float fs = fsum_ws[bvm];
    float agg = a * node + edge;
    float h = fmaxf(0.f, W_l[(size_t)r * RED + r] * agg + b_l[r]);
    atomicAdd(&h_g[b * RED + r], h);
    atomicAdd(&h_p[b * RED + r], fs * h);
}

// ---------- kernel 4: final FC + sigmoid (transposed weights, split-j) ----------
__global__ __launch_bounds__(256) void k_out(
        const float* __restrict__ h_g, const float* __restrict__ h_p,
        const float* __restrict__ fcWT, const float* __restrict__ fc_b,
        float* __restrict__ out) {
    int b   = blockIdx.x;
    int tid = threadIdx.x;                    // 256
    __shared__ float z[2 * RED];
    __shared__ float part[2][OUTD];
    for (int j = tid; j < RED; j += 256) {
        z[j]       = h_g[b * RED + j];
        z[RED + j] = h_p[b * RED + j];
    }
    __syncthreads();
    int o = tid & 127, half = tid >> 7;
    if (o < OUTD) {
        float acc = 0.f;
        int j0 = half * RED;
        #pragma unroll 8
        for (int j = j0; j < j0 + RED; ++j)
            acc += z[j] * fcWT[j * OUTD + o];     // coalesced over o
        part[half][o] = acc;
    }
    __syncthreads();
    if (tid < OUTD) {
        float acc = part[0][tid] + part[1][tid] + fc_b[tid];
        out[b * OUTD + tid] = 1.f / (1.f + expf(-acc));
    }
}

extern "C" void kernel_launch(void* const* d_in, const int* in_sizes, int n_in,
                              void* d_out, int out_size, void* d_ws, size_t ws_size,
                              hipStream_t stream) {
    const float* feat    = (const float*)d_in[0];
    const float* nbr     = (const float*)d_in[1];
    const float* rel     = (const float*)d_in[2];
    const float* emb     = (const float*)d_in[3];
    const float* W_edge  = (const float*)d_in[4];
    const float* W_v     = (const float*)d_in[5];
    const float* W_r     = (const float*)d_in[6];
    const float* b_v     = (const float*)d_in[7];
    const float* b_r     = (const float*)d_in[8];
    const float* W_alpha = (const float*)d_in[9];
    const float* b_alpha = (const float*)d_in[10];
    const float* W_beta  = (const float*)d_in[11];
    const float* b_beta  = (const float*)d_in[12];
    const float* W_l     = (const float*)d_in[13];
    const float* b_l     = (const float*)d_in[14];
    const float* fc_W    = (const float*)d_in[15];
    const float* fc_b    = (const float*)d_in[16];

    float* ws    = (float*)d_ws;
    float* hg    = ws + WS_HG;
    float* hp    = ws + WS_HP;
    float* attn  = ws + WS_ATTN;
    float* fsum  = ws + WS_FSUM;
    float* remb  = ws + WS_REMB;
    float* redge = ws + WS_REDGE;
    float* WT_v  = ws + WS_WTV;
    float* WT_r  = ws + WS_WTR;
    float* fcWT  = ws + WS_FCWT;

    k_prep_attn<<<PREP_BLOCKS + BS * NV, 256, 0, stream>>>(
        W_v, W_r, fc_W, feat, W_alpha, b_alpha, W_beta, b_beta,
        ws, WT_v, WT_r, fcWT, attn, fsum);
    k_reduce<<<NODE_BLOCKS + NR, 256, 0, stream>>>(
        emb, W_edge, WT_v, WT_r, b_v, b_r, remb, redge);
    k_agg<<<BS * NV * MF, 256, 0, stream>>>(
        nbr, rel, remb, redge, attn, fsum, W_l, b_l, hg, hp);
    k_out<<<BS, 256, 0, stream>>>(hg, hp, fcWT, fc_b, (float*)d_out);
}

// Round 4
// 447.801 us; speedup vs baseline: 1.2085x; 1.0150x over previous
//
#include <hip/hip_runtime.h>
#include <math.h>

#define BS   32
#define NV   6
#define MF   12
#define MT   16
#define NF   1992
#define NR   11
#define HID  128
#define RED  256
#define OUTD 90
#define GAMMA 0.1f
#define NZCAP 1024

typedef float f4_t __attribute__((ext_vector_type(4)));

// workspace layout (float offsets)
#define WS_HG    0                        // 32*256
#define WS_HP    (WS_HG + BS*RED)         // 32*256
#define WS_ATTN  (WS_HP + BS*RED)         // 2304
#define WS_FSUM  (WS_ATTN + BS*NV*MF)     // 2304
#define WS_REMB  (WS_FSUM + BS*NV*MF)     // 1992*256
#define WS_REDGE (WS_REMB + NF*RED)       // 11*256
#define WS_WTV   (WS_REDGE + NR*RED)      // 128*256  (W_v^T, k-major)
#define WS_WTR   (WS_WTV + HID*RED)       // 128*256  (W_r^T, k-major)
#define WS_FCWT  (WS_WTR + HID*RED)       // 512*90   (fc_W^T, j-major)
#define WS_DIAG  (WS_FCWT + 2*RED*OUTD)   // 256      (diag of W_l)
#define WS_CNT   (WS_DIAG + RED)          // 2304 ints
#define WS_RSUM  (WS_CNT + BS*NV*MF)      // 2304*11
#define WS_NZN   (WS_RSUM + BS*NV*MF*NR)  // 2304*1024 ints
#define WS_NZV   (WS_NZN + BS*NV*MF*NZCAP)// 2304*1024 floats

#define STREAM_BLOCKS (BS*NV*MF)          // 2304
#define N_ZERO (2*BS*RED)                 // 16384 (hg+hp contiguous)
#define N_WTV  (HID*RED)                  // 32768
#define N_WTR  (HID*RED)                  // 32768
#define N_FCWT (2*RED*OUTD)               // 46080
#define N_DIAG RED                        // 256
#define PREP_ELEMS (N_ZERO + N_WTV + N_WTR + N_FCWT + N_DIAG)   // 128256
#define PREP_BLOCKS (PREP_ELEMS / 256)                          // 501

// ---------- K1: nbr stream+compact  |  zero+transposes+diag  |  attention ----------
__global__ __launch_bounds__(256) void k_stream_prep_attn(
        const float* __restrict__ nbr, const float* __restrict__ rel,
        const float* __restrict__ W_v, const float* __restrict__ W_r,
        const float* __restrict__ fc_W, const float* __restrict__ W_l,
        const float* __restrict__ feat, const float* __restrict__ W_alpha,
        const float* __restrict__ b_alpha, const float* __restrict__ W_beta,
        const float* __restrict__ b_beta,
        float* __restrict__ ws_base,
        float* __restrict__ WT_v, float* __restrict__ WT_r, float* __restrict__ fcWT,
        float* __restrict__ diag,
        int* __restrict__ cnt_g, float* __restrict__ rsum_g,
        int* __restrict__ nzn_g, float* __restrict__ nzv_g,
        float* __restrict__ attn_ws, float* __restrict__ fsum_ws) {
    int blk = blockIdx.x;
    int tid = threadIdx.x;

    if (blk < STREAM_BLOCKS) {
        // ---- the 294 MB long pole: stream nbr, sum over t, compact nonzeros ----
        int bvm = blk;
        __shared__ int   nz_n[NZCAP];
        __shared__ float nz_v[NZCAP];
        __shared__ int   cnt;
        if (tid == 0) cnt = 0;
        const f4_t* base = (const f4_t*)(nbr + (size_t)bvm * MT * NF);  // row = 498 f4
        f4_t a0 = (f4_t)(0.f);
        f4_t a1 = (f4_t)(0.f);
        const bool has1 = (tid + 256) < (NF / 4);
        #pragma unroll 4
        for (int t = 0; t < MT; ++t) {
            const f4_t* r4 = base + t * (NF / 4);
            a0 += __builtin_nontemporal_load(r4 + tid);
            if (has1) a1 += __builtin_nontemporal_load(r4 + tid + 256);
        }
        float rs = 0.f;
        if (tid < NR) {
            const float* rb = rel + (size_t)bvm * MT * NR;
            #pragma unroll
            for (int t = 0; t < MT; ++t) rs += rb[t * NR + tid];
        }
        __syncthreads();   // covers cnt=0
        int nb = tid * 4;
        #pragma unroll
        for (int c = 0; c < 4; ++c)
            if (a0[c] != 0.f) {
                int p = atomicAdd(&cnt, 1);
                if (p < NZCAP) { nz_n[p] = nb + c; nz_v[p] = a0[c]; }
            }
        if (has1) {
            nb = (tid + 256) * 4;
            #pragma unroll
            for (int c = 0; c < 4; ++c)
                if (a1[c] != 0.f) {
                    int p = atomicAdd(&cnt, 1);
                    if (p < NZCAP) { nz_n[p] = nb + c; nz_v[p] = a1[c]; }
                }
        }
        __syncthreads();
        int c = min(cnt, NZCAP);
        if (tid == 0) cnt_g[bvm] = c;
        if (tid < NR) rsum_g[bvm * NR + tid] = rs;
        for (int i = tid; i < c; i += 256) {
            nzn_g[bvm * NZCAP + i] = nz_n[i];
            nzv_g[bvm * NZCAP + i] = nz_v[i];
        }
        return;
    }
    blk -= STREAM_BLOCKS;

    if (blk < PREP_BLOCKS) {
        int i = blk * 256 + tid;
        if (i < N_ZERO) {                          // zero hg+hp
            ws_base[i] = 0.f;
        } else if (i < N_ZERO + N_WTV) {           // WT_v[k*256+r] = W_v[r*128+k]
            int j = i - N_ZERO;
            int k = j >> 8, r = j & 255;
            WT_v[j] = W_v[r * HID + k];
        } else if (i < N_ZERO + N_WTV + N_WTR) {
            int j = i - (N_ZERO + N_WTV);
            int k = j >> 8, r = j & 255;
            WT_r[j] = W_r[r * HID + k];
        } else if (i < N_ZERO + N_WTV + N_WTR + N_FCWT) {
            int j = i - (N_ZERO + N_WTV + N_WTR);  // j = jj*90 + o
            int jj = j / OUTD, o = j - jj * OUTD;
            fcWT[j] = fc_W[o * (2 * RED) + jj];
        } else {
            int j = i - (N_ZERO + N_WTV + N_WTR + N_FCWT);
            diag[j] = W_l[(size_t)j * RED + j];
        }
        return;
    }

    // ---- attention: one block per (b,v), one wave per m ----
    int bv   = blk - PREP_BLOCKS;                  // 0..191
    int v    = bv % NV;
    int wave = tid >> 6;
    int lane = tid & 63;
    __shared__ float dot12[MF], fs12[MF];
    const float* base = feat + (size_t)bv * MF * NF;
    for (int m = wave; m < MF; m += 4) {
        const float4* rw = (const float4*)(base + (size_t)m * NF);   // 498 float4
        const float4* wa = (const float4*)W_alpha;
        float da = 0.f, fs = 0.f;
        for (int i = lane; i < NF / 4; i += 64) {
            float4 x = rw[i];
            float4 w = wa[i];
            da += w.x * x.x + w.y * x.y + w.z * x.z + w.w * x.w;
            fs += x.x + x.y + x.z + x.w;
        }
        #pragma unroll
        for (int off = 32; off > 0; off >>= 1) {
            da += __shfl_xor(da, off);
            fs += __shfl_xor(fs, off);
        }
        if (lane == 0) { dot12[m] = da; fs12[m] = fs; }
    }
    __syncthreads();
    if (tid == 0) {
        float logits[MF];
        float mx = -1e30f;
        for (int m = 0; m < MF; ++m) { logits[m] = dot12[m] + b_alpha[m]; mx = fmaxf(mx, logits[m]); }
        float s = 0.f;
        for (int m = 0; m < MF; ++m) { logits[m] = expf(logits[m] - mx); s += logits[m]; }
        float inv = 1.f / s;
        float bdot = 0.f;
        for (int m = 0; m < MF; ++m) { logits[m] *= inv; bdot += W_beta[m] * logits[m]; }
        float lamb = expf(-GAMMA * (float)(NV - v));
        float beta = tanhf(bdot + b_beta[v]) * lamb;
        for (int m = 0; m < MF; ++m) {
            attn_ws[bv * MF + m] = logits[m] * beta;
            fsum_ws[bv * MF + m] = fs12[m];
        }
    }
}

// ---------- K2: reduced_emb (8 rows/block) + reduced_edge ----------
#define NPB 8
#define NODE_BLOCKS (NF / NPB)   // 249
__global__ __launch_bounds__(256) void k_reduce(
        const float* __restrict__ emb, const float* __restrict__ W_edge,
        const float* __restrict__ WT_v, const float* __restrict__ WT_r,
        const float* __restrict__ b_v, const float* __restrict__ b_r,
        float* __restrict__ remb, float* __restrict__ redge) {
    int blk = blockIdx.x;
    int tid = threadIdx.x;                    // r = tid
    if (blk < NODE_BLOCKS) {
        __shared__ float rows[NPB][HID];
        int n0 = blk * NPB;
        for (int i = tid; i < NPB * HID; i += 256)
            rows[i >> 7][i & 127] = emb[(size_t)n0 * HID + i];
        __syncthreads();
        float bv0 = b_v[tid];
        float a0 = bv0, a1 = bv0, a2 = bv0, a3 = bv0;
        float a4 = bv0, a5 = bv0, a6 = bv0, a7 = bv0;
        #pragma unroll 4
        for (int k = 0; k < HID; ++k) {
            float w = WT_v[k * RED + tid];    // coalesced, L2-resident
            a0 += rows[0][k] * w;
            a1 += rows[1][k] * w;
            a2 += rows[2][k] * w;
            a3 += rows[3][k] * w;
            a4 += rows[4][k] * w;
            a5 += rows[5][k] * w;
            a6 += rows[6][k] * w;
            a7 += rows[7][k] * w;
        }
        float* dst = remb + (size_t)n0 * RED + tid;
        dst[0*RED] = a0; dst[1*RED] = a1; dst[2*RED] = a2; dst[3*RED] = a3;
        dst[4*RED] = a4; dst[5*RED] = a5; dst[6*RED] = a6; dst[7*RED] = a7;
    } else {
        int e = blk - NODE_BLOCKS;            // 0..10
        __shared__ float row[HID];
        if (tid < HID) row[tid] = W_edge[e * HID + tid];
        __syncthreads();
        float acc = b_r[tid];
        #pragma unroll 4
        for (int k = 0; k < HID; ++k)
            acc += row[k] * WT_r[k * RED + tid];
        redge[e * RED + tid] = acc;
    }
}

// ---------- K3: sparse gather + diag/relu + atomic accumulate ----------
__global__ __launch_bounds__(256) void k_gather(
        const float* __restrict__ remb, const float* __restrict__ redge,
        const int* __restrict__ cnt_g, const float* __restrict__ rsum_g,
        const int* __restrict__ nzn_g, const float* __restrict__ nzv_g,
        const float* __restrict__ attn_ws, const float* __restrict__ fsum_ws,
        const float* __restrict__ diag, const float* __restrict__ b_l,
        float* __restrict__ h_g, float* __restrict__ h_p) {
    int bvm = blockIdx.x;                     // 0..2303
    int b   = bvm / (NV * MF);
    int tid = threadIdx.x;                    // r = tid
    __shared__ int   nz_n[NZCAP];
    __shared__ float nz_v[NZCAP];
    __shared__ float rsum[NR];
    int c = cnt_g[bvm];
    if (tid < NR) rsum[tid] = rsum_g[bvm * NR + tid];
    for (int i = tid; i < c; i += 256) {
        nz_n[i] = nzn_g[bvm * NZCAP + i];
        nz_v[i] = nzv_g[bvm * NZCAP + i];
    }
    __syncthreads();
    int r = tid;
    float node = 0.f;
    for (int i = 0; i < c; ++i)
        node += nz_v[i] * remb[(size_t)nz_n[i] * RED + r];   // coalesced over r
    float edge = 0.f;
    #pragma unroll
    for (int j = 0; j < NR; ++j)
        edge += rsum[j] * redge[j * RED + r];
    float a  = attn_ws[bvm];
    float fs = fsum_ws[bvm];
    float agg = a * node + edge;
    float h = fmaxf(0.f, diag[r] * agg + b_l[r]);
    atomicAdd(&h_g[b * RED + r], h);
    atomicAdd(&h_p[b * RED + r], fs * h);
}

// ---------- K4: final FC + sigmoid ----------
__global__ __launch_bounds__(256) void k_out(
        const float* __restrict__ h_g, const float* __restrict__ h_p,
        const float* __restrict__ fcWT, const float* __restrict__ fc_b,
        float* __restrict__ out) {
    int b   = blockIdx.x;
    int tid = threadIdx.x;                    // 256
    __shared__ float z[2 * RED];
    __shared__ float part[2][OUTD];
    for (int j = tid; j < RED; j += 256) {
        z[j]       = h_g[b * RED + j];
        z[RED + j] = h_p[b * RED + j];
    }
    __syncthreads();
    int o = tid & 127, half = tid >> 7;
    if (o < OUTD) {
        float acc = 0.f;
        int j0 = half * RED;
        #pragma unroll 8
        for (int j = j0; j < j0 + RED; ++j)
            acc += z[j] * fcWT[j * OUTD + o];     // coalesced over o
        part[half][o] = acc;
    }
    __syncthreads();
    if (tid < OUTD) {
        float acc = part[0][tid] + part[1][tid] + fc_b[tid];
        out[b * OUTD + tid] = 1.f / (1.f + expf(-acc));
    }
}

extern "C" void kernel_launch(void* const* d_in, const int* in_sizes, int n_in,
                              void* d_out, int out_size, void* d_ws, size_t ws_size,
                              hipStream_t stream) {
    const float* feat    = (const float*)d_in[0];
    const float* nbr     = (const float*)d_in[1];
    const float* rel     = (const float*)d_in[2];
    const float* emb     = (const float*)d_in[3];
    const float* W_edge  = (const float*)d_in[4];
    const float* W_v     = (const float*)d_in[5];
    const float* W_r     = (const float*)d_in[6];
    const float* b_v     = (const float*)d_in[7];
    const float* b_r     = (const float*)d_in[8];
    const float* W_alpha = (const float*)d_in[9];
    const float* b_alpha = (const float*)d_in[10];
    const float* W_beta  = (const float*)d_in[11];
    const float* b_beta  = (const float*)d_in[12];
    const float* W_l     = (const float*)d_in[13];
    const float* b_l     = (const float*)d_in[14];
    const float* fc_W    = (const float*)d_in[15];
    const float* fc_b    = (const float*)d_in[16];

    float* ws    = (float*)d_ws;
    float* hg    = ws + WS_HG;
    float* hp    = ws + WS_HP;
    float* attn  = ws + WS_ATTN;
    float* fsum  = ws + WS_FSUM;
    float* remb  = ws + WS_REMB;
    float* redge = ws + WS_REDGE;
    float* WT_v  = ws + WS_WTV;
    float* WT_r  = ws + WS_WTR;
    float* fcWT  = ws + WS_FCWT;
    float* diag  = ws + WS_DIAG;
    int*   cnt_g = (int*)(ws + WS_CNT);
    float* rsum_g= ws + WS_RSUM;
    int*   nzn_g = (int*)(ws + WS_NZN);
    float* nzv_g = ws + WS_NZV;

    k_stream_prep_attn<<<STREAM_BLOCKS + PREP_BLOCKS + BS * NV, 256, 0, stream>>>(
        nbr, rel, W_v, W_r, fc_W, W_l, feat, W_alpha, b_alpha, W_beta, b_beta,
        ws, WT_v, WT_r, fcWT, diag, cnt_g, rsum_g, nzn_g, nzv_g, attn, fsum);
    k_reduce<<<NODE_BLOCKS + NR, 256, 0, stream>>>(
        emb, W_edge, WT_v, WT_r, b_v, b_r, remb, redge);
    k_gather<<<BS * NV * MF, 256, 0, stream>>>(
        remb, redge, cnt_g, rsum_g, nzn_g, nzv_g, attn, fsum, diag, b_l, hg, hp);
    k_out<<<BS, 256, 0, stream>>>(hg, hp, fcWT, fc_b, (float*)d_out);
}